// Round 1
// baseline (368.644 us; speedup 1.0000x reference)
//
#include <hip/hip_runtime.h>

// AnalyticalBoundedLineAttractor:
//   per step: z = W x + b; m = (z>0); Z = dt*(diag(m)W - I); c = dt*(m.*b)
//   x_next = e^Z x + phi1(Z) c   (phi1(Z) = sum Z^k/(k+1)!)
// Augmented-series recurrence (one matvec per Taylor term):
//   w1 = Z x + c = dt*(m.*z) - dt*x      (reuses the mask matvec)
//   wk = Z w_{k-1} / k,  k = 2..K
//   x_next = x + sum_k wk
// ||Z|| <~ 0.15, so K=6 terms -> truncation ~3e-9 per step (threshold 7.7e-2).
//
// Mapping: one 64-lane wave per batch element (256 blocks x 64 threads).
// Lane i holds row i of W in 64 VGPRs; the vector being multiplied is
// broadcast through a double-buffered LDS array (same-address reads are
// conflict-free broadcasts). One single-wave barrier per matvec.

#define DT_F 0.05f
#define T_STEPS 100
#define DD 64
#define KT 6  // Taylor terms w_1..w_KT

__global__ __launch_bounds__(64, 1)
void abla_kernel(const float* __restrict__ x0,
                 const float* __restrict__ W,
                 const float* __restrict__ bvec,
                 float* __restrict__ out) {
    const int batch = blockIdx.x;
    const int lane = threadIdx.x;

    __shared__ float sv[2][DD];

    // Lane i caches row i of W in registers (all indices compile-time ->
    // stays in VGPRs; 64 VGPRs).
    float Wr[DD];
#pragma unroll
    for (int j = 0; j < DD; j += 4) {
        const float4 w4 = *reinterpret_cast<const float4*>(W + lane * DD + j);
        Wr[j + 0] = w4.x; Wr[j + 1] = w4.y; Wr[j + 2] = w4.z; Wr[j + 3] = w4.w;
    }
    const float bi = bvec[lane];
    float x = x0[batch * DD + lane];
    float* outp = out + (size_t)batch * T_STEPS * DD + lane;

    for (int t = 0; t < T_STEPS; ++t) {
        // Trajectory stores the state BEFORE the update.
        outp[(size_t)t * DD] = x;

        // ---- term k=1: matvec v = W x (also gives the mask) ----
        sv[0][lane] = x;
        __syncthreads();
        float a0 = 0.f, a1 = 0.f, a2 = 0.f, a3 = 0.f;
#pragma unroll
        for (int j = 0; j < DD; j += 4) {
            a0 = fmaf(Wr[j + 0], sv[0][j + 0], a0);
            a1 = fmaf(Wr[j + 1], sv[0][j + 1], a1);
            a2 = fmaf(Wr[j + 2], sv[0][j + 2], a2);
            a3 = fmaf(Wr[j + 3], sv[0][j + 3], a3);
        }
        const float z = ((a0 + a1) + (a2 + a3)) + bi;
        // Fold dt into the mask: m_dt = m_i ? dt : 0
        const float m_dt = (z > 0.f) ? DT_F : 0.f;
        float w = m_dt * z - DT_F * x;   // w1 = dt*(m.*z) - dt*x
        float y = x + w;

        // ---- terms k=2..KT: w <- Z w / k ----
#pragma unroll
        for (int k = 2; k <= KT; ++k) {
            const int p = (k - 1) & 1;  // alternate buffers; write is to the
            sv[p][lane] = w;            // buffer last read two terms ago (safe)
            __syncthreads();
            const float* sw = sv[p];
            float c0 = 0.f, c1 = 0.f, c2 = 0.f, c3 = 0.f;
#pragma unroll
            for (int j = 0; j < DD; j += 4) {
                c0 = fmaf(Wr[j + 0], sw[j + 0], c0);
                c1 = fmaf(Wr[j + 1], sw[j + 1], c1);
                c2 = fmaf(Wr[j + 2], sw[j + 2], c2);
                c3 = fmaf(Wr[j + 3], sw[j + 3], c3);
            }
            const float v = (c0 + c1) + (c2 + c3);
            w = (m_dt * v - DT_F * w) * (1.0f / (float)k);
            y += w;
        }
        x = y;
        __syncthreads();  // protect sv[0] before next step's broadcast write
    }
}

extern "C" void kernel_launch(void* const* d_in, const int* in_sizes, int n_in,
                              void* d_out, int out_size, void* d_ws, size_t ws_size,
                              hipStream_t stream) {
    const float* x0 = (const float*)d_in[0];   // (256, 64) f32
    const float* W  = (const float*)d_in[1];   // (64, 64)  f32
    const float* b  = (const float*)d_in[2];   // (64,)     f32
    float* out = (float*)d_out;                // (256, 100, 64) f32

    const int batch = in_sizes[0] / DD;        // 256
    abla_kernel<<<batch, DD, 0, stream>>>(x0, W, b, out);
}

// Round 2
// 154.745 us; speedup vs baseline: 2.3823x; 2.3823x over previous
//
#include <hip/hip_runtime.h>

// AnalyticalBoundedLineAttractor — exact linear-regime stepping via Taylor
// recurrence (see round-1 derivation):
//   z = Wx + b; m_dt = (z>0)?dt:0
//   w1 = m_dt*z - dt*x;  wk = (m_dt*(W w) - dt*w)/k;  x+ = x + sum wk
// ||Z|| <= dt*(||W||+1) ~ 0.15 -> K=4 terms, truncation ~6e-7/step.
//
// Matvec with ZERO LDS/barriers in the chain: lane i pre-loads the rotated
// row Wr[k] = W[i][(i-k)&63]; the operand vector is rotated in-register with
// DPP wave_ror:1 (lane i <- lane i-1, same direction as the row_shr scan
// idiom). Two 32-deep rotate chains (second seeded by shfl_xor 32 == rotate
// by 32) halve the critical path; bpermute latency overlaps chain A.

#define DT_F 0.05f
#define T_STEPS 100
#define DD 64
#define KT 4  // Taylor terms w_1..w_KT

__device__ __forceinline__ float ror1(float v) {
    int i = __float_as_int(v);
    // dpp_ctrl 0x13C = wave_ror:1, row_mask=0xF, bank_mask=0xF, bound_ctrl=1
    i = __builtin_amdgcn_update_dpp(i, i, 0x13C, 0xF, 0xF, true);
    return __int_as_float(i);
}

// v_i = sum_j W[i][j] * w[j]; requires Wr[k] = W[lane][(lane-k)&63]
__device__ __forceinline__ float matvec64(const float (&Wr)[DD], float w) {
    float ra = w;                        // chain A: offsets k = 0..31
    float rb = __shfl_xor(w, 32, 64);    // chain B: offsets k = 32..63
    float a0 = Wr[0] * ra;
    float b0 = Wr[32] * rb;
    float a1 = 0.f, b1 = 0.f;
#pragma unroll
    for (int r = 1; r < 32; ++r) {
        ra = ror1(ra);
        rb = ror1(rb);
        if (r & 1) {
            a1 = fmaf(Wr[r], ra, a1);
            b1 = fmaf(Wr[32 + r], rb, b1);
        } else {
            a0 = fmaf(Wr[r], ra, a0);
            b0 = fmaf(Wr[32 + r], rb, b0);
        }
    }
    return (a0 + a1) + (b0 + b1);
}

__global__ __launch_bounds__(64, 1)
void abla_kernel(const float* __restrict__ x0,
                 const float* __restrict__ W,
                 const float* __restrict__ bvec,
                 float* __restrict__ out) {
    const int batch = blockIdx.x;
    const int lane = threadIdx.x;

    // One-time: stage W coalesced into LDS, then pull the rotated row layout
    // into registers. (lane*64 + (lane-k)) % 32 = (lane-k) % 32 -> 2 lanes
    // per bank = conflict-free broadcast-free reads.
    __shared__ float sW[DD * DD];
    for (int idx = lane; idx < DD * DD; idx += DD) sW[idx] = W[idx];
    __syncthreads();

    float Wr[DD];
#pragma unroll
    for (int k = 0; k < DD; ++k)
        Wr[k] = sW[lane * DD + ((lane - k) & 63)];

    const float bi = bvec[lane];
    float x = x0[batch * DD + lane];
    float* outp = out + (size_t)batch * T_STEPS * DD + lane;

    for (int t = 0; t < T_STEPS; ++t) {
        // Trajectory stores the state BEFORE the update (off critical path).
        outp[(size_t)t * DD] = x;

        // term 1: z = Wx + b gives the regime mask
        const float z = matvec64(Wr, x) + bi;
        const float m_dt = (z > 0.f) ? DT_F : 0.f;
        float w = m_dt * z - DT_F * x;
        float y = x + w;

        // terms 2..KT
#pragma unroll
        for (int k = 2; k <= KT; ++k) {
            const float v = matvec64(Wr, w);
            w = (m_dt * v - DT_F * w) * (1.0f / (float)k);
            y += w;
        }
        x = y;
    }
}

extern "C" void kernel_launch(void* const* d_in, const int* in_sizes, int n_in,
                              void* d_out, int out_size, void* d_ws, size_t ws_size,
                              hipStream_t stream) {
    const float* x0 = (const float*)d_in[0];   // (256, 64) f32
    const float* W  = (const float*)d_in[1];   // (64, 64)  f32
    const float* b  = (const float*)d_in[2];   // (64,)     f32
    float* out = (float*)d_out;                // (256, 100, 64) f32

    const int batch = in_sizes[0] / DD;        // 256
    abla_kernel<<<batch, DD, 0, stream>>>(x0, W, b, out);
}

// Round 3
// 118.633 us; speedup vs baseline: 3.1074x; 1.3044x over previous
//
#include <hip/hip_runtime.h>

// AnalyticalBoundedLineAttractor — exact linear-regime stepping via Taylor
// recurrence:
//   z = Wx + b; m_dt = (z>0)?dt:0
//   w1 = m_dt*z - dt*x;  wk = (m_dt*(W w) - dt*w)/k;  x+ = x + sum wk
// ||Z|| <= dt*(||W||_2+1) ~ 0.15 -> K=3 terms, local truncation ~2e-5/step,
// accumulated ~6e-3 (threshold 7.7e-2; non-expansive dynamics, no blowup).
//
// Matvec: broadcast form. Lane i holds row i of W in 64 VGPRs (natural
// order). w_j is broadcast to all lanes via v_readlane (SGPR), and lane i
// accumulates v_i = sum_j Wr[j]*w_j locally — no cross-lane reduction, no
// LDS, no barriers, and the 64 readlanes are mutually INDEPENDENT (unlike
// R2's 31-deep serial DPP rotate chain, which stalled ~350 cyc/matvec).
// 4 interleaved accumulators give 16-cyc dep-reuse gaps >> 4-cyc FMA latency
// -> issue-bound: ~128 instr * 2 cyc ~ 260 cyc/matvec.

#define DT_F 0.05f
#define T_STEPS 100
#define DD 64
#define KT 3  // Taylor terms w_1..w_KT

__device__ __forceinline__ float matvec64(const float (&Wr)[DD], float w) {
    const int wi = __float_as_int(w);
    float a0 = 0.f, a1 = 0.f, a2 = 0.f, a3 = 0.f;
#pragma unroll
    for (int j = 0; j < DD; j += 4) {
        const float s0 = __int_as_float(__builtin_amdgcn_readlane(wi, j + 0));
        const float s1 = __int_as_float(__builtin_amdgcn_readlane(wi, j + 1));
        const float s2 = __int_as_float(__builtin_amdgcn_readlane(wi, j + 2));
        const float s3 = __int_as_float(__builtin_amdgcn_readlane(wi, j + 3));
        a0 = fmaf(Wr[j + 0], s0, a0);
        a1 = fmaf(Wr[j + 1], s1, a1);
        a2 = fmaf(Wr[j + 2], s2, a2);
        a3 = fmaf(Wr[j + 3], s3, a3);
    }
    return (a0 + a1) + (a2 + a3);
}

__global__ __launch_bounds__(64, 1)
void abla_kernel(const float* __restrict__ x0,
                 const float* __restrict__ W,
                 const float* __restrict__ bvec,
                 float* __restrict__ out) {
    const int batch = blockIdx.x;
    const int lane = threadIdx.x;

    // Lane i caches row i of W (natural order) in 64 VGPRs. One-time load;
    // stride-256B across lanes is uncoalesced but only ~147 KB total fetch.
    float Wr[DD];
#pragma unroll
    for (int j = 0; j < DD; j += 4) {
        const float4 w4 = *reinterpret_cast<const float4*>(W + lane * DD + j);
        Wr[j + 0] = w4.x; Wr[j + 1] = w4.y; Wr[j + 2] = w4.z; Wr[j + 3] = w4.w;
    }
    const float bi = bvec[lane];
    float x = x0[batch * DD + lane];
    float* outp = out + (size_t)batch * T_STEPS * DD + lane;

    for (int t = 0; t < T_STEPS; ++t) {
        // Trajectory stores the state BEFORE the update (off critical path).
        outp[(size_t)t * DD] = x;

        // term 1: z = Wx + b gives the regime mask
        const float z = matvec64(Wr, x) + bi;
        const float m_dt = (z > 0.f) ? DT_F : 0.f;
        float w = m_dt * z - DT_F * x;
        float y = x + w;

        // terms 2..KT
#pragma unroll
        for (int k = 2; k <= KT; ++k) {
            const float v = matvec64(Wr, w);
            w = (m_dt * v - DT_F * w) * (1.0f / (float)k);
            y += w;
        }
        x = y;
    }
}

extern "C" void kernel_launch(void* const* d_in, const int* in_sizes, int n_in,
                              void* d_out, int out_size, void* d_ws, size_t ws_size,
                              hipStream_t stream) {
    const float* x0 = (const float*)d_in[0];   // (256, 64) f32
    const float* W  = (const float*)d_in[1];   // (64, 64)  f32
    const float* b  = (const float*)d_in[2];   // (64,)     f32
    float* out = (float*)d_out;                // (256, 100, 64) f32

    const int batch = in_sizes[0] / DD;        // 256
    abla_kernel<<<batch, DD, 0, stream>>>(x0, W, b, out);
}